// Round 1
// 684.592 us; speedup vs baseline: 1.0115x; 1.0115x over previous
//
#include <hip/hip_runtime.h>
#include <hip/hip_bf16.h>

#define DIM  1024
#define RANK 256
#define NTOK 16384   // BATCH * SEQ = 4 * 4096

typedef __attribute__((ext_vector_type(8))) short short8;   // 8 bf16 = 4 VGPRs
typedef __attribute__((ext_vector_type(4))) float f32x4;

__device__ __forceinline__ short f2bf(float f) {
    __hip_bfloat16 h = __float2bfloat16(f);   // round-to-nearest-even
    return *(short*)&h;
}

// ---------------------------------------------------------------------------
// Prep (fused): blocks [0,2048) gather+convert A rows -> Ag[t][r] bf16;
//               blocks [2048,2176) transpose+convert B -> Bt[d][r] bf16.
// One launch instead of two; the two halves run concurrently.
// ---------------------------------------------------------------------------
__global__ void prep_kernel(const int* __restrict__ x,
                            const float* __restrict__ A,
                            const float* __restrict__ B,
                            __hip_bfloat16* __restrict__ Ag,
                            __hip_bfloat16* __restrict__ Bt) {
    if (blockIdx.x < 2048) {
        // Ag[t][r] = bf16(A[x[t]][r]); 32 threads/token, 8 ranks each.
        int idx = blockIdx.x * 256 + threadIdx.x;   // [0, 16384*32)
        int t   = idx >> 5;
        int r0  = (idx & 31) * 8;
        int tok = x[t];
        const float* src = A + (long)tok * RANK + r0;
        short8 v;
#pragma unroll
        for (int j = 0; j < 8; ++j)
            ((short*)&v)[j] = f2bf(src[j]);
        *(short8*)((short*)Ag + t * RANK + r0) = v;
    } else {
        // Bt[d][r] = bf16(B[r][d]); lanes sweep consecutive d -> coalesced.
        int idx   = (blockIdx.x - 2048) * 256 + threadIdx.x;   // [0, 32768)
        int dtile = idx >> 11;          // 16 tiles of 64 cols
        int w     = idx & 2047;
        int d     = dtile * 64 + (w & 63);
        int r0    = (w >> 6) * 8;       // 32 groups of 8 rows
        short8 v;
#pragma unroll
        for (int j = 0; j < 8; ++j)
            ((short*)&v)[j] = f2bf(B[(r0 + j) * DIM + d]);
        *(short8*)((short*)Bt + d * RANK + r0) = v;
    }
}

// ---------------------------------------------------------------------------
// Pass 1: Out[t][d] = W[x[t]][d] + Ag[t][:] @ Bt[d][:]   (fp32 out)
// 1-D grid of 1024 blocks, XCD-swizzled: logical block l = bx*8 + by with
// bx = token-block [0,128), by = dim-block [0,8). HW round-robins dispatch
// index n over 8 XCDs; l = (n%8)*128 + n/8 gives XCD k the chunk
// l in [128k, 128(k+1)) = bx in [16k,16k+16) x all by. Per-XCD L2 set:
// Ag slice 16*128*256*2B = 1 MB + whole Bt 512 KB  (fits 4 MB L2).
// W / out are touch-once -> non-temporal, so they don't evict Ag/Bt.
// Block = 256 threads = 4 waves in 2x2; wave tile 64x64 = 4x4 frags of
// 16x16; K = 256 = 8 MFMA k-steps; operands direct-from-global (L2-hot).
// ---------------------------------------------------------------------------
__global__ void emb_gemm_kernel(const int* __restrict__ x,
                                const float* __restrict__ W,
                                const __hip_bfloat16* __restrict__ Ag,
                                const __hip_bfloat16* __restrict__ Bt,
                                float* __restrict__ out) {
    __shared__ int xs[128];
    const int n  = blockIdx.x;                 // [0, 1024)
    const int l  = (n & 7) * 128 + (n >> 3);   // bijective: 1024 % 8 == 0
    const int t0 = (l >> 3) * 128;             // bx * 128
    const int n0 = (l & 7) * 128;              // by * 128
    const int tid = threadIdx.x;

    if (tid < 128) xs[tid] = x[t0 + tid];
    __syncthreads();

    const int lane = tid & 63;
    const int wv   = tid >> 6;
    const int wi   = wv >> 1;      // token-dim half (0..1)
    const int wj   = wv & 1;       // dim half (0..1)
    const int l15  = lane & 15;
    const int quad = lane >> 4;

    // A-operand: frag[j] = Ag[t0 + row][k0 + quad*8 + j]  (contiguous rows)
    const short* aptr[4];
#pragma unroll
    for (int i = 0; i < 4; ++i)
        aptr[i] = (const short*)Ag + (t0 + wi * 64 + i * 16 + l15) * RANK + quad * 8;
    // B-operand: frag[j] = B[k][col] = Bt[col][k0 + quad*8 + j]
    const short* bptr[4];
#pragma unroll
    for (int j = 0; j < 4; ++j)
        bptr[j] = (const short*)Bt + (n0 + wj * 64 + j * 16 + l15) * RANK + quad * 8;

    f32x4 acc[4][4] = {};

#pragma unroll
    for (int ks = 0; ks < 8; ++ks) {      // k0 = ks*32
        short8 a[4], b[4];
#pragma unroll
        for (int i = 0; i < 4; ++i) a[i] = *(const short8*)(aptr[i] + ks * 32);
#pragma unroll
        for (int j = 0; j < 4; ++j) b[j] = *(const short8*)(bptr[j] + ks * 32);
#pragma unroll
        for (int i = 0; i < 4; ++i)
#pragma unroll
            for (int j = 0; j < 4; ++j)
                acc[i][j] = __builtin_amdgcn_mfma_f32_16x16x32_bf16(
                    a[i], b[j], acc[i][j], 0, 0, 0);
    }

    // Epilogue: C/D layout row = quad*4 + reg, col = lane&15 (m89/m91).
    // 16 consecutive lanes cover a 64 B segment of W / out -> coalesced.
    // W read and out write are touch-once: non-temporal keeps L2 for Ag/Bt.
#pragma unroll
    for (int i = 0; i < 4; ++i) {
#pragma unroll
        for (int jj = 0; jj < 4; ++jj) {
            const int lr   = wi * 64 + i * 16 + quad * 4 + jj;   // local row
            const int tokr = xs[lr];
            const float* wrow = W + (long)tokr * DIM;
            float* orow = out + (long)(t0 + lr) * DIM;
#pragma unroll
            for (int j = 0; j < 4; ++j) {
                const int c = n0 + wj * 64 + j * 16 + l15;
                const float wval = __builtin_nontemporal_load(wrow + c);
                __builtin_nontemporal_store(wval + acc[i][j][jj], orow + c);
            }
        }
    }
}

extern "C" void kernel_launch(void* const* d_in, const int* in_sizes, int n_in,
                              void* d_out, int out_size, void* d_ws, size_t ws_size,
                              hipStream_t stream) {
    const int*   x = (const int*)d_in[0];
    const float* W = (const float*)d_in[1];
    const float* A = (const float*)d_in[2];
    const float* B = (const float*)d_in[3];
    float* out     = (float*)d_out;

    __hip_bfloat16* Bt = (__hip_bfloat16*)d_ws;                       // 512 KB
    __hip_bfloat16* Ag = (__hip_bfloat16*)((char*)d_ws + DIM * RANK * sizeof(short)); // 8 MB

    prep_kernel<<<2176, 256, 0, stream>>>(x, A, B, Ag, Bt);
    emb_gemm_kernel<<<1024, 256, 0, stream>>>(x, W, Ag, Bt, out);
}